// Round 10
// baseline (25761.826 us; speedup 1.0000x reference)
//
#include <hip/hip_runtime.h>
#include <hip/hip_fp16.h>

// Stacked GRU (T=50, B=1, H=256) on MI355X — round 10.
// Round-9 skeleton (reduction-free parallel dots, wave3 poller, wave1 Gx
// prefetch, XCC election). Changes:
//  (1) exchange publish = 4 atomic swaps to ONE copy (was 128 swaps to 32
//      copies); poll = plain sc0 loads (L1-bypass, no RMW serialization).
//  (2) LDS weight layout re-padded (row stride 68 u64, quad chunk at q*17)
//      to kill the 4-way bank conflict (3.6M SQ_LDS_BANK_CONFLICT in r9).
// Slow agent-scope tagged path kept as latched fallback.

#define T_STEPS 50
#define VIN 768
#define VF 128
#define MIN_ 2
#define H 256
#define G3 768

#define NB 32
#define BT 256
#define HJ 8
#define BAIL 4000000
#define NBLOCKS 264

typedef unsigned long long u64;

__device__ __forceinline__ float sigm(float x){
  x = fminf(fmaxf(x, -30.f), 30.f);
  return __builtin_amdgcn_rcpf(1.f + __expf(-x));
}
__device__ __forceinline__ float ftanh(float x){
  x = fminf(fmaxf(x, -9.f), 9.f);
  float e = __expf(2.f*x);
  return (e - 1.f) * __builtin_amdgcn_rcpf(e + 1.f);
}
__device__ __forceinline__ float eluf(float x){ return x > 0.0f ? x : expm1f(x); }

__device__ __forceinline__ u64 ald(const u64* p){
  return __hip_atomic_load(const_cast<u64*>(p), __ATOMIC_RELAXED, __HIP_MEMORY_SCOPE_AGENT);
}
__device__ __forceinline__ void ast(u64* p, u64 v){
  __hip_atomic_store(p, v, __ATOMIC_RELAXED, __HIP_MEMORY_SCOPE_AGENT);
}
__device__ __forceinline__ u64 packtv(unsigned tag, float v){
  union{ float f; unsigned u; } c; c.f = v;
  return ((u64)tag << 32) | (u64)c.u;
}
__device__ __forceinline__ float unpackv(u64 x){
  union{ unsigned u; float f; } c; c.u = (unsigned)x; return c.f;
}

// 4 f16 MACs: w8/h8 each hold 4 halfs; accumulate into f32.
typedef _Float16 h2_t __attribute__((ext_vector_type(2)));
__device__ __forceinline__ float dot4h(u64 w8, u64 h8, float acc){
#if __has_builtin(__builtin_amdgcn_fdot2)
  union{ u64 x; h2_t v[2]; } cw, ch;
  cw.x = w8; ch.x = h8;
  acc = __builtin_amdgcn_fdot2(cw.v[0], ch.v[0], acc, false);
  acc = __builtin_amdgcn_fdot2(cw.v[1], ch.v[1], acc, false);
#else
  union{ u64 x; __half2 v[2]; } cw, ch;
  cw.x = w8; ch.x = h8;
  float2 a0=__half22float2(cw.v[0]), b0=__half22float2(ch.v[0]);
  float2 a1=__half22float2(cw.v[1]), b1=__half22float2(ch.v[1]);
  acc += a0.x*b0.x + a0.y*b0.y + a1.x*b1.x + a1.y*b1.y;
#endif
  return acc;
}

// fast poll: plain sc0 loads (bypass L1, read XCD L2 directly) of the
// single swap-published copy. 2 loads/lane/iter, zero RMW traffic.
__device__ __forceinline__ bool poll_fast_ld(const u64* base, int lane, unsigned tag,
                                             unsigned* hu, int tries){
  const u64* p = base + lane;
  for (int i = 0; i < tries; ++i){
    u64 x0, x1;
    asm volatile(
      "global_load_dwordx2 %0, %2, off sc0\n\t"
      "global_load_dwordx2 %1, %3, off sc0\n\t"
      "s_waitcnt vmcnt(0)"
      : "=&v"(x0), "=&v"(x1)
      : "v"(p), "v"(p+64)
      : "memory");
    bool ok = (((unsigned)(x0>>32))==tag) & (((unsigned)(x1>>32))==tag);
    if (__all(ok)){
      hu[lane]      = (unsigned)x0;
      hu[64 + lane] = (unsigned)x1;
      return true;
    }
  }
  return false;
}

// slow poll: agent-scope grouped loads on f32 tagged array; deposit as f16.
__device__ __forceinline__ void poll_slow(const u64* base, int lane, unsigned tag, unsigned* hu){
  __half* hp = (__half*)hu;
  const u64* p = base + lane;
  int guard = 0;
  while (true){
    u64 x0 = ald(p), x1 = ald(p+64), x2 = ald(p+128), x3 = ald(p+192);
    bool ok = (((unsigned)(x0>>32))==tag) & (((unsigned)(x1>>32))==tag)
            & (((unsigned)(x2>>32))==tag) & (((unsigned)(x3>>32))==tag);
    if (ok | (++guard > BAIL)){
      hp[      lane] = __float2half(unpackv(x0));
      hp[ 64 + lane] = __float2half(unpackv(x1));
      hp[128 + lane] = __float2half(unpackv(x2));
      hp[192 + lane] = __float2half(unpackv(x3));
      break;
    }
    if (guard > 2000) __builtin_amdgcn_s_sleep(1);
  }
}

__global__ __launch_bounds__(BT) void fused_kernel(
    const float* __restrict__ v0, const float* __restrict__ m0,
    const float* __restrict__ W1v, const float* __restrict__ b1v,
    const float* __restrict__ W1m, const float* __restrict__ b1m,
    const float* __restrict__ Wih_low, const float* __restrict__ Whh_low,
    const float* __restrict__ bih_low, const float* __restrict__ bhh_low,
    const float* __restrict__ Wih_high, const float* __restrict__ Whh_high,
    const float* __restrict__ bih_high, const float* __restrict__ bhh_high,
    const float* __restrict__ W2v, const float* __restrict__ b2v,
    const float* __restrict__ W2m, const float* __restrict__ b2m,
    float* __restrict__ out,
    u64* h1xf, u64* h2xf, u64* h1xs, u64* h2xs,
    u64* gxt, u64* h1ot, unsigned* ectl)
{
  // weights: 4 mats x 24 rows; row = 4 quad-chunks of 16 u64 padded to 17
  // (bank offset 2 mod 32 per quad -> conflict-free); row stride 68 u64.
  __shared__ u64 wlds8[96*68];                  // 52224 B
  __shared__ alignas(8) unsigned h1u[128];      // h1 as half2 entries
  __shared__ alignas(8) unsigned h2u[128];
  __shared__ float giA_l[24], ghA_l[24], giB_l[24], ghB_l[24];
  __shared__ float gx_lds[48];                  // [par][24]
  __shared__ float xbuf[H];
  __shared__ int s_role, s_idx;

  const int tid = threadIdx.x;
  const int wv = tid >> 6, lane = tid & 63;

  // ---------------- election: find one XCD with >=32 blocks (pigeonhole) ----
  if (tid == 0){
    unsigned xcd;
    asm volatile("s_getreg_b32 %0, hwreg(HW_REG_XCC_ID, 0, 32)" : "=s"(xcd));
    xcd &= 7u;
    unsigned tk = atomicAdd(&ectl[xcd], 1u);
    if (tk == 31u) atomicCAS(&ectl[8], 0u, xcd + 1u);
    unsigned ch; int guard = 0;
    while (!(ch = __hip_atomic_load(&ectl[8], __ATOMIC_RELAXED, __HIP_MEMORY_SCOPE_AGENT))){
      __builtin_amdgcn_s_sleep(2);
      if (++guard > BAIL){ ch = 1u; break; }
    }
    if (xcd == ch - 1u && tk < 32u){ s_role = 0; s_idx = (int)tk; }
    else {
      unsigned ak = atomicAdd(&ectl[9], 1u);
      if      (ak < 50u ){ s_role = 1; s_idx = (int)ak; }
      else if (ak < 100u){ s_role = 2; s_idx = (int)(ak - 50u); }
      else               { s_role = 3; s_idx = 0; }
    }
  }
  __syncthreads();
  const int role = s_role, idx = s_idx;
  if (role == 3) return;

  if (role == 0){
    // ================================================== scan role
    const int b = idx;
    // stage weights: m: 0=Wih_low[:,256:512] 1=Whh_low 2=Wih_high 3=Whh_high
    for (int i = tid; i < 96*64; i += BT){
      int gr = i >> 6, c = i & 63;
      int m = gr / 24, lr = gr - m*24;
      int gate = lr >> 3, j = lr & 7;
      int row = gate*H + b*HJ + j;
      int k = c*4;
      float4 f;
      if      (m == 0) f = *(const float4*)(Wih_low  + (size_t)row*512 + 256 + k);
      else if (m == 1) f = *(const float4*)(Whh_low  + (size_t)row*256 + k);
      else if (m == 2) f = *(const float4*)(Wih_high + (size_t)row*256 + k);
      else             f = *(const float4*)(Whh_high + (size_t)row*256 + k);
      union{ u64 x; __half2 v[2]; } pk;
      pk.v[0] = __floats2half2_rn(f.x, f.y);
      pk.v[1] = __floats2half2_rn(f.z, f.w);
      wlds8[gr*68 + (c >> 4)*17 + (c & 15)] = pk.x;
    }
    if (tid < 24){ giA_l[tid]=0.f; ghA_l[tid]=0.f; giB_l[tid]=0.f; ghB_l[tid]=0.f; }

    float hv1 = 0.f, hv2 = 0.f;
    float blR=0,blZ=0,blN=0, biR=0,biZ=0,biN=0, bhR=0,bhZ=0,bhN=0;
    bool fast_ok1 = true, fast_ok2 = true;    // wave3 latches
    const int jg = b*HJ + lane;               // valid for lane<HJ
    if (wv == 0 && lane < HJ){
      blR = bhh_low [jg]; blZ = bhh_low [H+jg]; blN = bhh_low [2*H+jg];
      biR = bih_high[jg]; biZ = bih_high[H+jg]; biN = bih_high[2*H+jg];
      bhR = bhh_high[jg]; bhZ = bhh_high[H+jg]; bhN = bhh_high[2*H+jg];
      const u64* g = gxt + jg;                // Gx[0] -> gx_lds[0..23]
      int guard = 0;
      while (true){
        u64 a0 = ald(g), a1 = ald(g + H), a2 = ald(g + 2*H);
        bool ok = (((unsigned)(a0>>32))==1u) & (((unsigned)(a1>>32))==1u) & (((unsigned)(a2>>32))==1u);
        if (ok | (++guard > BAIL)){
          gx_lds[lane] = unpackv(a0); gx_lds[8+lane] = unpackv(a1); gx_lds[16+lane] = unpackv(a2);
          break;
        }
        __builtin_amdgcn_s_sleep(4);
      }
    }
    __syncthreads();

    const int gr = wv*16 + (lane >> 2);       // P-phase row (waves 0-2)
    const int q  = lane & 3;

    for (int t = 0; t < T_STEPS; ++t){
      const int par = t & 1;
      const unsigned tag = (unsigned)(t + 1);

      // ---- seg_a: wave0 finalize A + publish | wave1 Gx[t+1] | wave3 poll h1
      if (wv == 0){
        float hnew = hv1;
        if (lane < HJ){
          float giR = giA_l[lane]    + gx_lds[par*24 + lane];
          float giZ = giA_l[8+lane]  + gx_lds[par*24 + 8 + lane];
          float giN = giA_l[16+lane] + gx_lds[par*24 + 16 + lane];
          float ghR = ghA_l[lane]    + blR;
          float ghZ = ghA_l[8+lane]  + blZ;
          float ghN = ghA_l[16+lane] + blN;
          float r = sigm(giR + ghR), z = sigm(giZ + ghZ);
          float n = ftanh(giN + r * ghN);
          hv1 = (1.f - z) * n + z * hv1;
          hnew = hv1;
        }
        float pa = __shfl(hnew, 2*(lane & 3));
        float pb = __shfl(hnew, 2*(lane & 3) + 1);
        if (lane < 4){
          union{ __half2 hh; unsigned u; } c; c.hh = __floats2half2_rn(pa, pb);
          u64 pk = ((u64)tag << 32) | (u64)c.u;
          u64* df = h1xf + par*128 + (b<<2) + lane;
          asm volatile("global_atomic_swap_x2 %0, %1, off" :: "v"(df), "v"(pk) : "memory");
        }
        if (lane < HJ){
          ast(h1xs + par*H + jg, packtv(tag, hv1));
          ast(h1ot + (size_t)t*H + jg, packtv(1u, hv1));   // cross-XCD to post
        }
      } else if (wv == 1){
        if (lane < HJ && t + 1 < T_STEPS){               // prefetch Gx[t+1]
          const u64* g = gxt + (size_t)(t+1)*G3 + jg;
          int guard = 0;
          while (true){
            u64 a0 = ald(g), a1 = ald(g + H), a2 = ald(g + 2*H);
            bool ok = (((unsigned)(a0>>32))==1u) & (((unsigned)(a1>>32))==1u) & (((unsigned)(a2>>32))==1u);
            if (ok | (++guard > BAIL)){
              int np = (1 - par) * 24;
              gx_lds[np + lane] = unpackv(a0); gx_lds[np + 8 + lane] = unpackv(a1); gx_lds[np + 16 + lane] = unpackv(a2);
              break;
            }
            __builtin_amdgcn_s_sleep(1);
          }
        }
      }
      if (t == T_STEPS - 1) break;
      if (wv == 3){
        bool got = false;
        if (fast_ok1){
          got = poll_fast_ld(h1xf + par*128, lane, tag, h1u, t==0 ? 30000 : 300000);
          fast_ok1 = got;
        }
        if (!got) poll_slow(h1xs + par*H, lane, tag, h1u);
      }
      __syncthreads();                                   // bar1: h1 ready

      // ---- P1: 48 rows on h1: gi_B (mat2) rows 0..23, gh_A' (mat1) rows 24..47
      if (wv < 3){
        int wr = (gr < 24) ? (48 + gr) : gr;             // mat2 base 48, mat1 base 24
        const u64* wrow = wlds8 + wr*68 + q*17;
        const u64* hh = reinterpret_cast<const u64*>(h1u) + q*16;
        float s = 0.f;
        #pragma unroll
        for (int i = 0; i < 16; ++i) s = dot4h(wrow[i], hh[i], s);
        s += __shfl_xor(s, 1);
        s += __shfl_xor(s, 2);
        if (q == 0){ if (gr < 24) giB_l[gr] = s; else ghA_l[gr-24] = s; }
      }
      __syncthreads();                                   // bar2: gi_B/gh_A' ready

      // ---- seg_b: wave0 finalize B + publish | wave3 poll h2
      if (wv == 0){
        float hnew = hv2;
        if (lane < HJ){
          float giR = giB_l[lane]    + biR, ghR = ghB_l[lane]    + bhR;
          float giZ = giB_l[8+lane]  + biZ, ghZ = ghB_l[8+lane]  + bhZ;
          float giN = giB_l[16+lane] + biN, ghN = ghB_l[16+lane] + bhN;
          float r = sigm(giR + ghR), z = sigm(giZ + ghZ);
          float n = ftanh(giN + r * ghN);
          hv2 = (1.f - z) * n + z * hv2;
          hnew = hv2;
        }
        float pa = __shfl(hnew, 2*(lane & 3));
        float pb = __shfl(hnew, 2*(lane & 3) + 1);
        if (lane < 4){
          union{ __half2 hh; unsigned u; } c; c.hh = __floats2half2_rn(pa, pb);
          u64 pk = ((u64)tag << 32) | (u64)c.u;
          u64* df = h2xf + par*128 + (b<<2) + lane;
          asm volatile("global_atomic_swap_x2 %0, %1, off" :: "v"(df), "v"(pk) : "memory");
        }
        if (lane < HJ) ast(h2xs + par*H + jg, packtv(tag, hv2));
      } else if (wv == 3){
        bool got = false;
        if (fast_ok2){
          got = poll_fast_ld(h2xf + par*128, lane, tag, h2u, t==0 ? 30000 : 300000);
          fast_ok2 = got;
        }
        if (!got) poll_slow(h2xs + par*H, lane, tag, h2u);
      }
      __syncthreads();                                   // bar3: h2 ready

      // ---- P2: 48 rows on h2: gi_A' (mat0) rows 0..23, gh_B' (mat3) rows 24..47
      if (wv < 3){
        int wr = (gr < 24) ? gr : (48 + gr);             // mat0 base 0, mat3 base 72
        const u64* wrow = wlds8 + wr*68 + q*17;
        const u64* hh = reinterpret_cast<const u64*>(h2u) + q*16;
        float s = 0.f;
        #pragma unroll
        for (int i = 0; i < 16; ++i) s = dot4h(wrow[i], hh[i], s);
        s += __shfl_xor(s, 1);
        s += __shfl_xor(s, 2);
        if (q == 0){ if (gr < 24) giA_l[gr] = s; else ghB_l[gr-24] = s; }
      }
      __syncthreads();                                   // bar4
    }

  } else if (role == 1){
    // ================================================== featgx role
    const int t = idx;
    { int j = tid >> 1, s = tid & 1;
      const float4* a4 = reinterpret_cast<const float4*>(v0 + (size_t)t*VIN) + s*96;
      const float4* w4 = reinterpret_cast<const float4*>(W1v + (size_t)j*VIN) + s*96;
      float p = 0.f;
      #pragma unroll 4
      for (int c = 0; c < 96; ++c){
        float4 a = a4[c], w = w4[c];
        p += a.x*w.x + a.y*w.y + a.z*w.z + a.w*w.w;
      }
      p += __shfl_xor(p, 1);
      if (s == 0) xbuf[j] = eluf(p + b1v[j]);
    }
    if (tid < VF){
      float am = b1m[tid] + W1m[tid*2]*m0[t*2] + W1m[tid*2+1]*m0[t*2+1];
      xbuf[VF + tid] = eluf(am);
    }
    __syncthreads();
    #pragma unroll
    for (int k = 0; k < 3; ++k){
      int r = k*256 + tid;
      const float4* w4 = reinterpret_cast<const float4*>(Wih_low + (size_t)r*(2*H));
      const float4* x4 = reinterpret_cast<const float4*>(xbuf);
      float acc = bih_low[r];
      #pragma unroll 8
      for (int c = 0; c < 64; ++c){
        float4 w = w4[c], x = x4[c];
        acc += w.x*x.x + w.y*x.y + w.z*x.z + w.w*x.w;
      }
      ast(gxt + (size_t)t*G3 + r, packtv(1u, acc));
    }

  } else {
    // ================================================== post role
    const int t = idx;
    for (int i = 0; i < t; ++i) __builtin_amdgcn_s_sleep(32);   // staggered start
    if (wv == 0){
      const u64* p = h1ot + (size_t)t*H + lane;
      int guard = 0;
      while (true){
        u64 x0 = ald(p), x1 = ald(p+64), x2 = ald(p+128), x3 = ald(p+192);
        bool ok = (((unsigned)(x0>>32))==1u) & (((unsigned)(x1>>32))==1u)
                & (((unsigned)(x2>>32))==1u) & (((unsigned)(x3>>32))==1u);
        if (ok | (++guard > BAIL)){
          xbuf[      lane] = eluf(unpackv(x0));
          xbuf[ 64 + lane] = eluf(unpackv(x1));
          xbuf[128 + lane] = eluf(unpackv(x2));
          xbuf[192 + lane] = eluf(unpackv(x3));
          break;
        }
        __builtin_amdgcn_s_sleep(8);
      }
    }
    __syncthreads();
    #pragma unroll
    for (int k = 0; k < 3; ++k){
      int r = k*256 + tid;
      const float4* w4 = reinterpret_cast<const float4*>(W2v + (size_t)r*VF);
      const float4* f4 = reinterpret_cast<const float4*>(xbuf);
      float acc = b2v[r];
      #pragma unroll 8
      for (int c = 0; c < 32; ++c){
        float4 w = w4[c], x = f4[c];
        acc += w.x*x.x + w.y*x.y + w.z*x.z + w.w*x.w;
      }
      out[(size_t)t*VIN + r] = sigm(acc);
    }
    if (tid < MIN_){
      const float* wm = W2m + tid*VF;
      float am = b2m[tid];
      #pragma unroll 8
      for (int c = 0; c < VF; ++c) am += wm[c] * xbuf[VF + c];
      out[(size_t)T_STEPS*VIN + t*MIN_ + tid] = tanhf(am);
    }
  }
}

extern "C" void kernel_launch(void* const* d_in, const int* in_sizes, int n_in,
                              void* d_out, int out_size, void* d_ws, size_t ws_size,
                              hipStream_t stream)
{
  const float* v0       = (const float*)d_in[0];
  const float* m0       = (const float*)d_in[1];
  const float* W1v      = (const float*)d_in[2];
  const float* b1v      = (const float*)d_in[3];
  const float* W1m      = (const float*)d_in[4];
  const float* b1m      = (const float*)d_in[5];
  const float* Wih_low  = (const float*)d_in[6];
  const float* Whh_low  = (const float*)d_in[7];
  const float* bih_low  = (const float*)d_in[8];
  const float* bhh_low  = (const float*)d_in[9];
  const float* Wih_high = (const float*)d_in[10];
  const float* Whh_high = (const float*)d_in[11];
  const float* bih_high = (const float*)d_in[12];
  const float* bhh_high = (const float*)d_in[13];
  const float* W2v      = (const float*)d_in[14];
  const float* b2v      = (const float*)d_in[15];
  const float* W2m      = (const float*)d_in[16];
  const float* b2m      = (const float*)d_in[17];
  float* out = (float*)d_out;

  // ws layout (8B-aligned). Poison 0xAA..AA != any tag used (1..50).
  // h1xf/h2xf (fast, f16-packed, SINGLE copy): [par][128] u64 = 2 KB each.
  // h1xs/h2xs (slow, f32 tagged): [par][256] u64 = 4 KB each.
  char* ws = (char*)d_ws;
  u64* h1xf     = (u64*)(ws + 0);               // 2 KB
  u64* h2xf     = (u64*)(ws + 2048);            // 2 KB
  u64* h1xs     = (u64*)(ws + 4096);            // 4 KB
  u64* h2xs     = (u64*)(ws + 8192);            // 4 KB
  u64* gxt      = (u64*)(ws + 12288);           // 300 KB
  u64* h1ot     = (u64*)(ws + 319488);          // 100 KB
  unsigned* ectl= (unsigned*)(ws + 421888);     // election counters

  hipMemsetAsync(ws + 421888, 0, 256, stream);  // zero election state only

  fused_kernel<<<NBLOCKS, BT, 0, stream>>>(
      v0, m0, W1v, b1v, W1m, b1m,
      Wih_low, Whh_low, bih_low, bhh_low,
      Wih_high, Whh_high, bih_high, bhh_high,
      W2v, b2v, W2m, b2m, out,
      h1xf, h2xf, h1xs, h2xs, gxt, h1ot, ectl);
}

// Round 11
// 421.750 us; speedup vs baseline: 61.0832x; 61.0832x over previous
//
#include <hip/hip_runtime.h>
#include <hip/hip_fp16.h>

// Stacked GRU (T=50, B=1, H=256) on MI355X — round 11.
// Round-9 skeleton (reduction-free parallel dots, wave1 Gx prefetch, wave3
// consumer, XCC election). Exchange REPLACED by flag-then-data:
//   producer: ast 4 f16-packed tagged entries (single copy) -> s_waitcnt
//             vmcnt(0) -> ONE non-returning atomicAdd to a step counter.
//   consumer: poll the counter with agent-scope loads (1 broadcast
//             request/iter — no RMW flood), then tag-verified agent loads of
//             the data. Kills the L2 atomic-pipe saturation that r9's
//             continuous 4096-RMW poll sweeps caused.
// NEVER plain/sc0 loads for cross-CU data (stale — proven r5/r10).

#define T_STEPS 50
#define VIN 768
#define VF 128
#define MIN_ 2
#define H 256
#define G3 768

#define NB 32
#define BT 256
#define HJ 8
#define BAIL 4000000
#define NBLOCKS 264

typedef unsigned long long u64;

__device__ __forceinline__ float sigm(float x){
  x = fminf(fmaxf(x, -30.f), 30.f);
  return __builtin_amdgcn_rcpf(1.f + __expf(-x));
}
__device__ __forceinline__ float ftanh(float x){
  x = fminf(fmaxf(x, -9.f), 9.f);
  float e = __expf(2.f*x);
  return (e - 1.f) * __builtin_amdgcn_rcpf(e + 1.f);
}
__device__ __forceinline__ float eluf(float x){ return x > 0.0f ? x : expm1f(x); }

__device__ __forceinline__ u64 ald(const u64* p){
  return __hip_atomic_load(const_cast<u64*>(p), __ATOMIC_RELAXED, __HIP_MEMORY_SCOPE_AGENT);
}
__device__ __forceinline__ unsigned ald32(const unsigned* p){
  return __hip_atomic_load(const_cast<unsigned*>(p), __ATOMIC_RELAXED, __HIP_MEMORY_SCOPE_AGENT);
}
__device__ __forceinline__ void ast(u64* p, u64 v){
  __hip_atomic_store(p, v, __ATOMIC_RELAXED, __HIP_MEMORY_SCOPE_AGENT);
}
__device__ __forceinline__ u64 packtv(unsigned tag, float v){
  union{ float f; unsigned u; } c; c.f = v;
  return ((u64)tag << 32) | (u64)c.u;
}
__device__ __forceinline__ float unpackv(u64 x){
  union{ unsigned u; float f; } c; c.u = (unsigned)x; return c.f;
}

// 4 f16 MACs: w8/h8 each hold 4 halfs; accumulate into f32.
typedef _Float16 h2_t __attribute__((ext_vector_type(2)));
__device__ __forceinline__ float dot4h(u64 w8, u64 h8, float acc){
#if __has_builtin(__builtin_amdgcn_fdot2)
  union{ u64 x; h2_t v[2]; } cw, ch;
  cw.x = w8; ch.x = h8;
  acc = __builtin_amdgcn_fdot2(cw.v[0], ch.v[0], acc, false);
  acc = __builtin_amdgcn_fdot2(cw.v[1], ch.v[1], acc, false);
#else
  union{ u64 x; __half2 v[2]; } cw, ch;
  cw.x = w8; ch.x = h8;
  float2 a0=__half22float2(cw.v[0]), b0=__half22float2(ch.v[0]);
  float2 a1=__half22float2(cw.v[1]), b1=__half22float2(ch.v[1]);
  acc += a0.x*b0.x + a0.y*b0.y + a1.x*b1.x + a1.y*b1.y;
#endif
  return acc;
}

__global__ __launch_bounds__(BT) void fused_kernel(
    const float* __restrict__ v0, const float* __restrict__ m0,
    const float* __restrict__ W1v, const float* __restrict__ b1v,
    const float* __restrict__ W1m, const float* __restrict__ b1m,
    const float* __restrict__ Wih_low, const float* __restrict__ Whh_low,
    const float* __restrict__ bih_low, const float* __restrict__ bhh_low,
    const float* __restrict__ Wih_high, const float* __restrict__ Whh_high,
    const float* __restrict__ bih_high, const float* __restrict__ bhh_high,
    const float* __restrict__ W2v, const float* __restrict__ b2v,
    const float* __restrict__ W2m, const float* __restrict__ b2m,
    float* __restrict__ out,
    u64* h1s, u64* h2s, u64* gxt, u64* h1ot, unsigned* ectl)
{
  // weights: 4 mats x 24 rows, row = 64 u64 chunks + 1 pad; r9 layout.
  __shared__ u64 wlds8[96*65];                  // 49920 B
  __shared__ alignas(8) unsigned h1u[128];      // h1 as half2 entries
  __shared__ alignas(8) unsigned h2u[128];
  __shared__ float giA_l[24], ghA_l[24], giB_l[24], ghB_l[24];
  __shared__ float gx_lds[48];                  // [par][24]
  __shared__ float xbuf[H];
  __shared__ int s_role, s_idx;

  const int tid = threadIdx.x;
  const int wv = tid >> 6, lane = tid & 63;
  unsigned* cnt4 = ectl + 32;                   // [h1p0,h1p1,h2p0,h2p1]

  // ---------------- election: find one XCD with >=32 blocks (pigeonhole) ----
  if (tid == 0){
    unsigned xcd;
    asm volatile("s_getreg_b32 %0, hwreg(HW_REG_XCC_ID, 0, 32)" : "=s"(xcd));
    xcd &= 7u;
    unsigned tk = atomicAdd(&ectl[xcd], 1u);
    if (tk == 31u) atomicCAS(&ectl[8], 0u, xcd + 1u);
    unsigned ch; int guard = 0;
    while (!(ch = ald32(&ectl[8]))){
      __builtin_amdgcn_s_sleep(2);
      if (++guard > BAIL){ ch = 1u; break; }
    }
    if (xcd == ch - 1u && tk < 32u){ s_role = 0; s_idx = (int)tk; }
    else {
      unsigned ak = atomicAdd(&ectl[9], 1u);
      if      (ak < 50u ){ s_role = 1; s_idx = (int)ak; }
      else if (ak < 100u){ s_role = 2; s_idx = (int)(ak - 50u); }
      else               { s_role = 3; s_idx = 0; }
    }
  }
  __syncthreads();
  const int role = s_role, idx = s_idx;
  if (role == 3) return;

  if (role == 0){
    // ================================================== scan role
    const int b = idx;
    // stage weights: m: 0=Wih_low[:,256:512] 1=Whh_low 2=Wih_high 3=Whh_high
    for (int i = tid; i < 96*64; i += BT){
      int gr = i >> 6, c = i & 63;
      int m = gr / 24, lr = gr - m*24;
      int gate = lr >> 3, j = lr & 7;
      int row = gate*H + b*HJ + j;
      int k = c*4;
      float4 f;
      if      (m == 0) f = *(const float4*)(Wih_low  + (size_t)row*512 + 256 + k);
      else if (m == 1) f = *(const float4*)(Whh_low  + (size_t)row*256 + k);
      else if (m == 2) f = *(const float4*)(Wih_high + (size_t)row*256 + k);
      else             f = *(const float4*)(Whh_high + (size_t)row*256 + k);
      union{ u64 x; __half2 v[2]; } pk;
      pk.v[0] = __floats2half2_rn(f.x, f.y);
      pk.v[1] = __floats2half2_rn(f.z, f.w);
      wlds8[gr*65 + c] = pk.x;
    }
    if (tid < 24){ giA_l[tid]=0.f; ghA_l[tid]=0.f; giB_l[tid]=0.f; ghB_l[tid]=0.f; }

    float hv1 = 0.f, hv2 = 0.f;
    float blR=0,blZ=0,blN=0, biR=0,biZ=0,biN=0, bhR=0,bhZ=0,bhN=0;
    const int jg = b*HJ + lane;               // valid for lane<HJ
    if (wv == 0 && lane < HJ){
      blR = bhh_low [jg]; blZ = bhh_low [H+jg]; blN = bhh_low [2*H+jg];
      biR = bih_high[jg]; biZ = bih_high[H+jg]; biN = bih_high[2*H+jg];
      bhR = bhh_high[jg]; bhZ = bhh_high[H+jg]; bhN = bhh_high[2*H+jg];
      const u64* g = gxt + jg;                // Gx[0] -> gx_lds[0..23]
      int guard = 0;
      while (true){
        u64 a0 = ald(g), a1 = ald(g + H), a2 = ald(g + 2*H);
        bool ok = (((unsigned)(a0>>32))==1u) & (((unsigned)(a1>>32))==1u) & (((unsigned)(a2>>32))==1u);
        if (ok | (++guard > BAIL)){
          gx_lds[lane] = unpackv(a0); gx_lds[8+lane] = unpackv(a1); gx_lds[16+lane] = unpackv(a2);
          break;
        }
        __builtin_amdgcn_s_sleep(4);
      }
    }
    __syncthreads();

    const int gr = wv*16 + (lane >> 2);       // P-phase row (waves 0-2)
    const int q  = lane & 3;

    for (int t = 0; t < T_STEPS; ++t){
      const int par = t & 1;
      const unsigned tag = (unsigned)(t + 1);
      const unsigned target = (unsigned)(((t >> 1) + 1) * NB);

      // ---- seg_a: wave0 finalize A + publish(flag-then-data) | wave1 Gx[t+1]
      //              | wave3 counter-poll + data-fetch h1
      if (wv == 0){
        float hnew = hv1;
        if (lane < HJ){
          float giR = giA_l[lane]    + gx_lds[par*24 + lane];
          float giZ = giA_l[8+lane]  + gx_lds[par*24 + 8 + lane];
          float giN = giA_l[16+lane] + gx_lds[par*24 + 16 + lane];
          float ghR = ghA_l[lane]    + blR;
          float ghZ = ghA_l[8+lane]  + blZ;
          float ghN = ghA_l[16+lane] + blN;
          float r = sigm(giR + ghR), z = sigm(giZ + ghZ);
          float n = ftanh(giN + r * ghN);
          hv1 = (1.f - z) * n + z * hv1;
          hnew = hv1;
        }
        if (t == T_STEPS - 1){
          if (lane < HJ) ast(h1ot + (size_t)t*H + jg, packtv(1u, hv1));
        } else {
          float pa = __shfl(hnew, 2*(lane & 3));
          float pb = __shfl(hnew, 2*(lane & 3) + 1);
          if (lane < 4){
            union{ __half2 hh; unsigned u; } c; c.hh = __floats2half2_rn(pa, pb);
            ast(h1s + par*128 + (b<<2) + lane, ((u64)tag << 32) | (u64)c.u);
          }
          asm volatile("s_waitcnt vmcnt(0)" ::: "memory");   // data before flag
          if (lane == 0) atomicAdd(&cnt4[par], 1u);
        }
      } else if (wv == 1){
        if (lane < HJ && t + 1 < T_STEPS){               // prefetch Gx[t+1]
          const u64* g = gxt + (size_t)(t+1)*G3 + jg;
          int guard = 0;
          while (true){
            u64 a0 = ald(g), a1 = ald(g + H), a2 = ald(g + 2*H);
            bool ok = (((unsigned)(a0>>32))==1u) & (((unsigned)(a1>>32))==1u) & (((unsigned)(a2>>32))==1u);
            if (ok | (++guard > BAIL)){
              int np = (1 - par) * 24;
              gx_lds[np + lane] = unpackv(a0); gx_lds[np + 8 + lane] = unpackv(a1); gx_lds[np + 16 + lane] = unpackv(a2);
              break;
            }
            __builtin_amdgcn_s_sleep(1);
          }
        }
      }
      if (t == T_STEPS - 1) break;
      if (wv == 3){
        // counter poll: one broadcast agent load per iteration
        int guard = 0;
        while (ald32(&cnt4[par]) < target){
          if (++guard > BAIL) break;
          if (guard > 50000) __builtin_amdgcn_s_sleep(1);
        }
        // data fetch (tag-verified)
        const u64* p = h1s + par*128 + lane;
        guard = 0;
        u64 x0, x1;
        while (true){
          x0 = ald(p); x1 = ald(p + 64);
          bool ok = (((unsigned)(x0>>32))==tag) & (((unsigned)(x1>>32))==tag);
          if (__all(ok) | (++guard > BAIL)){
            h1u[lane]      = (unsigned)x0;
            h1u[64 + lane] = (unsigned)x1;
            break;
          }
        }
        if (b == 0){                                     // publish h1ot for post
          union{ unsigned u; __half2 hh; } c0, c1;
          c0.u = (unsigned)x0; c1.u = (unsigned)x1;
          float2 f0 = __half22float2(c0.hh);
          float2 f1 = __half22float2(c1.hh);
          u64* o = h1ot + (size_t)t*H;
          ast(o + 2*lane,       packtv(1u, f0.x));
          ast(o + 2*lane + 1,   packtv(1u, f0.y));
          ast(o + 128 + 2*lane, packtv(1u, f1.x));
          ast(o + 129 + 2*lane, packtv(1u, f1.y));
        }
      }
      __syncthreads();                                   // bar1: h1 ready

      // ---- P1: 48 rows on h1: gi_B (mat2) rows 0..23, gh_A' (mat1) rows 24..47
      if (wv < 3){
        int wr = (gr < 24) ? (48 + gr) : gr;             // mat2 base 48, mat1 base 24
        const u64* wrow = wlds8 + wr*65 + q*16;
        const u64* hh = reinterpret_cast<const u64*>(h1u) + q*16;
        float s = 0.f;
        #pragma unroll
        for (int i = 0; i < 16; ++i) s = dot4h(wrow[i], hh[i], s);
        s += __shfl_xor(s, 1);
        s += __shfl_xor(s, 2);
        if (q == 0){ if (gr < 24) giB_l[gr] = s; else ghA_l[gr-24] = s; }
      }
      __syncthreads();                                   // bar2: gi_B/gh_A' ready

      // ---- seg_b: wave0 finalize B + publish | wave3 counter-poll + fetch h2
      if (wv == 0){
        float hnew = hv2;
        if (lane < HJ){
          float giR = giB_l[lane]    + biR, ghR = ghB_l[lane]    + bhR;
          float giZ = giB_l[8+lane]  + biZ, ghZ = ghB_l[8+lane]  + bhZ;
          float giN = giB_l[16+lane] + biN, ghN = ghB_l[16+lane] + bhN;
          float r = sigm(giR + ghR), z = sigm(giZ + ghZ);
          float n = ftanh(giN + r * ghN);
          hv2 = (1.f - z) * n + z * hv2;
          hnew = hv2;
        }
        float pa = __shfl(hnew, 2*(lane & 3));
        float pb = __shfl(hnew, 2*(lane & 3) + 1);
        if (lane < 4){
          union{ __half2 hh; unsigned u; } c; c.hh = __floats2half2_rn(pa, pb);
          ast(h2s + par*128 + (b<<2) + lane, ((u64)tag << 32) | (u64)c.u);
        }
        asm volatile("s_waitcnt vmcnt(0)" ::: "memory");
        if (lane == 0) atomicAdd(&cnt4[2 + par], 1u);
      } else if (wv == 3){
        int guard = 0;
        while (ald32(&cnt4[2 + par]) < target){
          if (++guard > BAIL) break;
          if (guard > 50000) __builtin_amdgcn_s_sleep(1);
        }
        const u64* p = h2s + par*128 + lane;
        guard = 0;
        while (true){
          u64 x0 = ald(p), x1 = ald(p + 64);
          bool ok = (((unsigned)(x0>>32))==tag) & (((unsigned)(x1>>32))==tag);
          if (__all(ok) | (++guard > BAIL)){
            h2u[lane]      = (unsigned)x0;
            h2u[64 + lane] = (unsigned)x1;
            break;
          }
        }
      }
      __syncthreads();                                   // bar3: h2 ready

      // ---- P2: 48 rows on h2: gi_A' (mat0) rows 0..23, gh_B' (mat3) rows 24..47
      if (wv < 3){
        int wr = (gr < 24) ? gr : (48 + gr);             // mat0 base 0, mat3 base 72
        const u64* wrow = wlds8 + wr*65 + q*16;
        const u64* hh = reinterpret_cast<const u64*>(h2u) + q*16;
        float s = 0.f;
        #pragma unroll
        for (int i = 0; i < 16; ++i) s = dot4h(wrow[i], hh[i], s);
        s += __shfl_xor(s, 1);
        s += __shfl_xor(s, 2);
        if (q == 0){ if (gr < 24) giA_l[gr] = s; else ghB_l[gr-24] = s; }
      }
      __syncthreads();                                   // bar4
    }

  } else if (role == 1){
    // ================================================== featgx role
    const int t = idx;
    { int j = tid >> 1, s = tid & 1;
      const float4* a4 = reinterpret_cast<const float4*>(v0 + (size_t)t*VIN) + s*96;
      const float4* w4 = reinterpret_cast<const float4*>(W1v + (size_t)j*VIN) + s*96;
      float p = 0.f;
      #pragma unroll 4
      for (int c = 0; c < 96; ++c){
        float4 a = a4[c], w = w4[c];
        p += a.x*w.x + a.y*w.y + a.z*w.z + a.w*w.w;
      }
      p += __shfl_xor(p, 1);
      if (s == 0) xbuf[j] = eluf(p + b1v[j]);
    }
    if (tid < VF){
      float am = b1m[tid] + W1m[tid*2]*m0[t*2] + W1m[tid*2+1]*m0[t*2+1];
      xbuf[VF + tid] = eluf(am);
    }
    __syncthreads();
    #pragma unroll
    for (int k = 0; k < 3; ++k){
      int r = k*256 + tid;
      const float4* w4 = reinterpret_cast<const float4*>(Wih_low + (size_t)r*(2*H));
      const float4* x4 = reinterpret_cast<const float4*>(xbuf);
      float acc = bih_low[r];
      #pragma unroll 8
      for (int c = 0; c < 64; ++c){
        float4 w = w4[c], x = x4[c];
        acc += w.x*x.x + w.y*x.y + w.z*x.z + w.w*x.w;
      }
      ast(gxt + (size_t)t*G3 + r, packtv(1u, acc));
    }

  } else {
    // ================================================== post role
    const int t = idx;
    for (int i = 0; i < t; ++i) __builtin_amdgcn_s_sleep(32);   // staggered start
    if (wv == 0){
      const u64* p = h1ot + (size_t)t*H + lane;
      int guard = 0;
      while (true){
        u64 x0 = ald(p), x1 = ald(p+64), x2 = ald(p+128), x3 = ald(p+192);
        bool ok = (((unsigned)(x0>>32))==1u) & (((unsigned)(x1>>32))==1u)
                & (((unsigned)(x2>>32))==1u) & (((unsigned)(x3>>32))==1u);
        if (ok | (++guard > BAIL)){
          xbuf[      lane] = eluf(unpackv(x0));
          xbuf[ 64 + lane] = eluf(unpackv(x1));
          xbuf[128 + lane] = eluf(unpackv(x2));
          xbuf[192 + lane] = eluf(unpackv(x3));
          break;
        }
        __builtin_amdgcn_s_sleep(8);
      }
    }
    __syncthreads();
    #pragma unroll
    for (int k = 0; k < 3; ++k){
      int r = k*256 + tid;
      const float4* w4 = reinterpret_cast<const float4*>(W2v + (size_t)r*VF);
      const float4* f4 = reinterpret_cast<const float4*>(xbuf);
      float acc = b2v[r];
      #pragma unroll 8
      for (int c = 0; c < 32; ++c){
        float4 w = w4[c], x = f4[c];
        acc += w.x*x.x + w.y*x.y + w.z*x.z + w.w*x.w;
      }
      out[(size_t)t*VIN + r] = sigm(acc);
    }
    if (tid < MIN_){
      const float* wm = W2m + tid*VF;
      float am = b2m[tid];
      #pragma unroll 8
      for (int c = 0; c < VF; ++c) am += wm[c] * xbuf[VF + c];
      out[(size_t)T_STEPS*VIN + t*MIN_ + tid] = tanhf(am);
    }
  }
}

extern "C" void kernel_launch(void* const* d_in, const int* in_sizes, int n_in,
                              void* d_out, int out_size, void* d_ws, size_t ws_size,
                              hipStream_t stream)
{
  const float* v0       = (const float*)d_in[0];
  const float* m0       = (const float*)d_in[1];
  const float* W1v      = (const float*)d_in[2];
  const float* b1v      = (const float*)d_in[3];
  const float* W1m      = (const float*)d_in[4];
  const float* b1m      = (const float*)d_in[5];
  const float* Wih_low  = (const float*)d_in[6];
  const float* Whh_low  = (const float*)d_in[7];
  const float* bih_low  = (const float*)d_in[8];
  const float* bhh_low  = (const float*)d_in[9];
  const float* Wih_high = (const float*)d_in[10];
  const float* Whh_high = (const float*)d_in[11];
  const float* bih_high = (const float*)d_in[12];
  const float* bhh_high = (const float*)d_in[13];
  const float* W2v      = (const float*)d_in[14];
  const float* b2v      = (const float*)d_in[15];
  const float* W2m      = (const float*)d_in[16];
  const float* b2m      = (const float*)d_in[17];
  float* out = (float*)d_out;

  // ws layout (8B-aligned). Poison 0xAA..AA != any tag used (1..50).
  // h1s/h2s: [par][128] u64 f16-packed tagged data, single copy (2 KB each).
  // ectl: [0..7] XCD counters, [8] winner, [9] ticket, [32..35] step counters.
  char* ws = (char*)d_ws;
  u64* h1s      = (u64*)(ws + 0);               // 2 KB
  u64* h2s      = (u64*)(ws + 2048);            // 2 KB
  u64* gxt      = (u64*)(ws + 4096);            // 300 KB
  u64* h1ot     = (u64*)(ws + 311296);          // 100 KB
  unsigned* ectl= (unsigned*)(ws + 413696);     // election + step counters

  hipMemsetAsync(ws + 413696, 0, 256, stream);  // zero election/counter state

  fused_kernel<<<NBLOCKS, BT, 0, stream>>>(
      v0, m0, W1v, b1v, W1m, b1m,
      Wih_low, Whh_low, bih_low, bhh_low,
      Wih_high, Whh_high, bih_high, bhh_high,
      W2v, b2v, W2m, b2m, out,
      h1s, h2s, gxt, h1ot, ectl);
}

// Round 12
// 345.546 us; speedup vs baseline: 74.5541x; 1.2205x over previous
//
#include <hip/hip_runtime.h>
#include <hip/hip_fp16.h>

// Stacked GRU (T=50, B=1, H=256) on MI355X — round 12.
// r9 skeleton + single-RTT exchange without r9's taxes:
//  - publish: 4 atomic swaps to ONE copy (tag embedded = data+flag in one op)
//  - poll: returning add-0 sc0 directly on data (1-RTT detect), throttled
//    with s_sleep(1)/iter after iter 4 (kills r9's atomic-pipe saturation)
//  - LDS 4-way bank conflicts fixed on BOTH weight reads (68/17 padding) and
//    h-vector reads (padded 17-stride chunks)  [r9/r11: 3.6M conflicts]
//  - h1ot (scan->post) publish moved off the critical path (wave3, P1 slot)
// Proven-stale mechanisms (plain/sc0 loads for cross-CU data) not used.

#define T_STEPS 50
#define VIN 768
#define VF 128
#define MIN_ 2
#define H 256
#define G3 768

#define NB 32
#define BT 256
#define HJ 8
#define BAIL 4000000
#define NBLOCKS 264

typedef unsigned long long u64;

__device__ __forceinline__ float sigm(float x){
  x = fminf(fmaxf(x, -30.f), 30.f);
  return __builtin_amdgcn_rcpf(1.f + __expf(-x));
}
__device__ __forceinline__ float ftanh(float x){
  x = fminf(fmaxf(x, -9.f), 9.f);
  float e = __expf(2.f*x);
  return (e - 1.f) * __builtin_amdgcn_rcpf(e + 1.f);
}
__device__ __forceinline__ float eluf(float x){ return x > 0.0f ? x : expm1f(x); }

__device__ __forceinline__ u64 ald(const u64* p){
  return __hip_atomic_load(const_cast<u64*>(p), __ATOMIC_RELAXED, __HIP_MEMORY_SCOPE_AGENT);
}
__device__ __forceinline__ unsigned ald32(const unsigned* p){
  return __hip_atomic_load(const_cast<unsigned*>(p), __ATOMIC_RELAXED, __HIP_MEMORY_SCOPE_AGENT);
}
__device__ __forceinline__ void ast(u64* p, u64 v){
  __hip_atomic_store(p, v, __ATOMIC_RELAXED, __HIP_MEMORY_SCOPE_AGENT);
}
__device__ __forceinline__ u64 packtv(unsigned tag, float v){
  union{ float f; unsigned u; } c; c.f = v;
  return ((u64)tag << 32) | (u64)c.u;
}
__device__ __forceinline__ float unpackv(u64 x){
  union{ unsigned u; float f; } c; c.u = (unsigned)x; return c.f;
}

// 4 f16 MACs: w8/h8 each hold 4 halfs; accumulate into f32.
typedef _Float16 h2_t __attribute__((ext_vector_type(2)));
__device__ __forceinline__ float dot4h(u64 w8, u64 h8, float acc){
#if __has_builtin(__builtin_amdgcn_fdot2)
  union{ u64 x; h2_t v[2]; } cw, ch;
  cw.x = w8; ch.x = h8;
  acc = __builtin_amdgcn_fdot2(cw.v[0], ch.v[0], acc, false);
  acc = __builtin_amdgcn_fdot2(cw.v[1], ch.v[1], acc, false);
#else
  union{ u64 x; __half2 v[2]; } cw, ch;
  cw.x = w8; ch.x = h8;
  float2 a0=__half22float2(cw.v[0]), b0=__half22float2(ch.v[0]);
  float2 a1=__half22float2(cw.v[1]), b1=__half22float2(ch.v[1]);
  acc += a0.x*b0.x + a0.y*b0.y + a1.x*b1.x + a1.y*b1.y;
#endif
  return acc;
}

// single-RTT poll: returning add-0 (sc0 = return old) on the tagged data,
// 2 entries/lane, throttled after iter 4. Returns raw entries in x0/x1.
__device__ __forceinline__ bool poll_rmw2(u64* base, int lane, unsigned tag,
                                          u64& x0, u64& x1){
  u64* p = base + lane;
  u64 zero = 0;
  for (int i = 0; i < BAIL; ++i){
    asm volatile(
      "global_atomic_add_x2 %0, %2, %4, off sc0\n\t"
      "global_atomic_add_x2 %1, %3, %4, off sc0\n\t"
      "s_waitcnt vmcnt(0)"
      : "=&v"(x0), "=&v"(x1)
      : "v"(p), "v"(p+64), "v"(zero)
      : "memory");
    bool ok = (((unsigned)(x0>>32))==tag) & (((unsigned)(x1>>32))==tag);
    if (__all(ok)) return true;
    if (i > 4) __builtin_amdgcn_s_sleep(1);
  }
  return false;
}

// deposit entries k=lane and k=64+lane into a padded h array
// (u64 chunk q at q*17; u32 entry k -> u64 idx ((k>>1)>>4)*17+((k>>1)&15)).
__device__ __forceinline__ void deposit_h(u64* h8, int lane, u64 x0, u64 x1){
  unsigned* h32 = (unsigned*)h8;
  int k0 = lane, k1 = 64 + lane;
  int u0 = ((k0>>1)>>4)*17 + ((k0>>1)&15);
  int u1 = ((k1>>1)>>4)*17 + ((k1>>1)&15);
  h32[2*u0 + (k0&1)] = (unsigned)x0;
  h32[2*u1 + (k1&1)] = (unsigned)x1;
}

__global__ __launch_bounds__(BT) void fused_kernel(
    const float* __restrict__ v0, const float* __restrict__ m0,
    const float* __restrict__ W1v, const float* __restrict__ b1v,
    const float* __restrict__ W1m, const float* __restrict__ b1m,
    const float* __restrict__ Wih_low, const float* __restrict__ Whh_low,
    const float* __restrict__ bih_low, const float* __restrict__ bhh_low,
    const float* __restrict__ Wih_high, const float* __restrict__ Whh_high,
    const float* __restrict__ bih_high, const float* __restrict__ bhh_high,
    const float* __restrict__ W2v, const float* __restrict__ b2v,
    const float* __restrict__ W2m, const float* __restrict__ b2m,
    float* __restrict__ out,
    u64* h1s, u64* h2s, u64* gxt, u64* h1ot, unsigned* ectl)
{
  // weights: 4 mats x 24 rows; row = 4 chunks of 16 u64 padded to 17 -> 68.
  __shared__ u64 wlds8[96*68];                  // 52224 B
  __shared__ u64 h1u8[68], h2u8[68];            // padded h (f16), 544 B each
  __shared__ float giA_l[24], ghA_l[24], giB_l[24], ghB_l[24];
  __shared__ float gx_lds[48];                  // [par][24]
  __shared__ float xbuf[H];
  __shared__ int s_role, s_idx;

  const int tid = threadIdx.x;
  const int wv = tid >> 6, lane = tid & 63;

  // ---------------- election: find one XCD with >=32 blocks (pigeonhole) ----
  if (tid == 0){
    unsigned xcd;
    asm volatile("s_getreg_b32 %0, hwreg(HW_REG_XCC_ID, 0, 32)" : "=s"(xcd));
    xcd &= 7u;
    unsigned tk = atomicAdd(&ectl[xcd], 1u);
    if (tk == 31u) atomicCAS(&ectl[8], 0u, xcd + 1u);
    unsigned ch; int guard = 0;
    while (!(ch = ald32(&ectl[8]))){
      __builtin_amdgcn_s_sleep(2);
      if (++guard > BAIL){ ch = 1u; break; }
    }
    if (xcd == ch - 1u && tk < 32u){ s_role = 0; s_idx = (int)tk; }
    else {
      unsigned ak = atomicAdd(&ectl[9], 1u);
      if      (ak < 50u ){ s_role = 1; s_idx = (int)ak; }
      else if (ak < 100u){ s_role = 2; s_idx = (int)(ak - 50u); }
      else               { s_role = 3; s_idx = 0; }
    }
  }
  __syncthreads();
  const int role = s_role, idx = s_idx;
  if (role == 3) return;

  if (role == 0){
    // ================================================== scan role
    const int b = idx;
    // stage weights: m: 0=Wih_low[:,256:512] 1=Whh_low 2=Wih_high 3=Whh_high
    for (int i = tid; i < 96*64; i += BT){
      int gr = i >> 6, c = i & 63;
      int m = gr / 24, lr = gr - m*24;
      int gate = lr >> 3, j = lr & 7;
      int row = gate*H + b*HJ + j;
      int k = c*4;
      float4 f;
      if      (m == 0) f = *(const float4*)(Wih_low  + (size_t)row*512 + 256 + k);
      else if (m == 1) f = *(const float4*)(Whh_low  + (size_t)row*256 + k);
      else if (m == 2) f = *(const float4*)(Wih_high + (size_t)row*256 + k);
      else             f = *(const float4*)(Whh_high + (size_t)row*256 + k);
      union{ u64 x; __half2 v[2]; } pk;
      pk.v[0] = __floats2half2_rn(f.x, f.y);
      pk.v[1] = __floats2half2_rn(f.z, f.w);
      wlds8[gr*68 + (c>>4)*17 + (c&15)] = pk.x;
    }
    if (tid < 24){ giA_l[tid]=0.f; ghA_l[tid]=0.f; giB_l[tid]=0.f; ghB_l[tid]=0.f; }

    float hv1 = 0.f, hv2 = 0.f;
    float blR=0,blZ=0,blN=0, biR=0,biZ=0,biN=0, bhR=0,bhZ=0,bhN=0;
    const int jg = b*HJ + lane;               // valid for lane<HJ
    if (wv == 0 && lane < HJ){
      blR = bhh_low [jg]; blZ = bhh_low [H+jg]; blN = bhh_low [2*H+jg];
      biR = bih_high[jg]; biZ = bih_high[H+jg]; biN = bih_high[2*H+jg];
      bhR = bhh_high[jg]; bhZ = bhh_high[H+jg]; bhN = bhh_high[2*H+jg];
      const u64* g = gxt + jg;                // Gx[0] -> gx_lds[0..23]
      int guard = 0;
      while (true){
        u64 a0 = ald(g), a1 = ald(g + H), a2 = ald(g + 2*H);
        bool ok = (((unsigned)(a0>>32))==1u) & (((unsigned)(a1>>32))==1u) & (((unsigned)(a2>>32))==1u);
        if (ok | (++guard > BAIL)){
          gx_lds[lane] = unpackv(a0); gx_lds[8+lane] = unpackv(a1); gx_lds[16+lane] = unpackv(a2);
          break;
        }
        __builtin_amdgcn_s_sleep(4);
      }
    }
    __syncthreads();

    const int gr = wv*16 + (lane >> 2);       // P-phase row (waves 0-2)
    const int q  = lane & 3;
    u64 px0 = 0, px1 = 0;                     // wave3: last-polled h1 entries

    for (int t = 0; t < T_STEPS; ++t){
      const int par = t & 1;
      const unsigned tag = (unsigned)(t + 1);

      // ---- seg_a: wave0 finalize A + swap-publish | wave1 Gx[t+1] | wave3 poll h1
      if (wv == 0){
        float hnew = hv1;
        if (lane < HJ){
          float giR = giA_l[lane]    + gx_lds[par*24 + lane];
          float giZ = giA_l[8+lane]  + gx_lds[par*24 + 8 + lane];
          float giN = giA_l[16+lane] + gx_lds[par*24 + 16 + lane];
          float ghR = ghA_l[lane]    + blR;
          float ghZ = ghA_l[8+lane]  + blZ;
          float ghN = ghA_l[16+lane] + blN;
          float r = sigm(giR + ghR), z = sigm(giZ + ghZ);
          float n = ftanh(giN + r * ghN);
          hv1 = (1.f - z) * n + z * hv1;
          hnew = hv1;
        }
        if (t == T_STEPS - 1){
          if (lane < HJ) ast(h1ot + (size_t)t*H + jg, packtv(1u, hv1));
        } else {
          float pa = __shfl(hnew, 2*(lane & 3));
          float pb = __shfl(hnew, 2*(lane & 3) + 1);
          if (lane < 4){
            union{ __half2 hh; unsigned u; } c; c.hh = __floats2half2_rn(pa, pb);
            u64 pk = ((u64)tag << 32) | (u64)c.u;
            asm volatile("global_atomic_swap_x2 %0, %1, off"
                         :: "v"(h1s + par*128 + (b<<2) + lane), "v"(pk) : "memory");
          }
        }
      } else if (wv == 1){
        if (lane < HJ && t + 1 < T_STEPS){               // prefetch Gx[t+1]
          const u64* g = gxt + (size_t)(t+1)*G3 + jg;
          int guard = 0;
          while (true){
            u64 a0 = ald(g), a1 = ald(g + H), a2 = ald(g + 2*H);
            bool ok = (((unsigned)(a0>>32))==1u) & (((unsigned)(a1>>32))==1u) & (((unsigned)(a2>>32))==1u);
            if (ok | (++guard > BAIL)){
              int np = (1 - par) * 24;
              gx_lds[np + lane] = unpackv(a0); gx_lds[np + 8 + lane] = unpackv(a1); gx_lds[np + 16 + lane] = unpackv(a2);
              break;
            }
            __builtin_amdgcn_s_sleep(1);
          }
        }
      }
      if (t == T_STEPS - 1) break;
      if (wv == 3){
        poll_rmw2(h1s + par*128, lane, tag, px0, px1);
        deposit_h(h1u8, lane, px0, px1);
      }
      __syncthreads();                                   // bar1: h1 ready

      // ---- P1: 48 rows on h1: gi_B (mat2) rows 0..23, gh_A' (mat1) rows 24..47
      //      wave3: publish h1ot (off critical path, block 0 only)
      if (wv < 3){
        int wr = (gr < 24) ? (48 + gr) : gr;             // mat2 base 48, mat1 base 24
        const u64* wrow = wlds8 + wr*68 + q*17;
        const u64* hh = h1u8 + q*17;
        float s = 0.f;
        #pragma unroll
        for (int i = 0; i < 16; ++i) s = dot4h(wrow[i], hh[i], s);
        s += __shfl_xor(s, 1);
        s += __shfl_xor(s, 2);
        if (q == 0){ if (gr < 24) giB_l[gr] = s; else ghA_l[gr-24] = s; }
      } else if (b == 0){
        union{ unsigned u; __half2 hh; } c0, c1;
        c0.u = (unsigned)px0; c1.u = (unsigned)px1;
        float2 f0 = __half22float2(c0.hh);
        float2 f1 = __half22float2(c1.hh);
        u64* o = h1ot + (size_t)t*H;
        ast(o + 2*lane,       packtv(1u, f0.x));
        ast(o + 2*lane + 1,   packtv(1u, f0.y));
        ast(o + 128 + 2*lane, packtv(1u, f1.x));
        ast(o + 129 + 2*lane, packtv(1u, f1.y));
      }
      __syncthreads();                                   // bar2: gi_B/gh_A' ready

      // ---- seg_b: wave0 finalize B + swap-publish | wave3 poll h2
      if (wv == 0){
        float hnew = hv2;
        if (lane < HJ){
          float giR = giB_l[lane]    + biR, ghR = ghB_l[lane]    + bhR;
          float giZ = giB_l[8+lane]  + biZ, ghZ = ghB_l[8+lane]  + bhZ;
          float giN = giB_l[16+lane] + biN, ghN = ghB_l[16+lane] + bhN;
          float r = sigm(giR + ghR), z = sigm(giZ + ghZ);
          float n = ftanh(giN + r * ghN);
          hv2 = (1.f - z) * n + z * hv2;
          hnew = hv2;
        }
        float pa = __shfl(hnew, 2*(lane & 3));
        float pb = __shfl(hnew, 2*(lane & 3) + 1);
        if (lane < 4){
          union{ __half2 hh; unsigned u; } c; c.hh = __floats2half2_rn(pa, pb);
          u64 pk = ((u64)tag << 32) | (u64)c.u;
          asm volatile("global_atomic_swap_x2 %0, %1, off"
                       :: "v"(h2s + par*128 + (b<<2) + lane), "v"(pk) : "memory");
        }
      } else if (wv == 3){
        u64 y0, y1;
        poll_rmw2(h2s + par*128, lane, tag, y0, y1);
        deposit_h(h2u8, lane, y0, y1);
      }
      __syncthreads();                                   // bar3: h2 ready

      // ---- P2: 48 rows on h2: gi_A' (mat0) rows 0..23, gh_B' (mat3) rows 24..47
      if (wv < 3){
        int wr = (gr < 24) ? gr : (48 + gr);             // mat0 base 0, mat3 base 72
        const u64* wrow = wlds8 + wr*68 + q*17;
        const u64* hh = h2u8 + q*17;
        float s = 0.f;
        #pragma unroll
        for (int i = 0; i < 16; ++i) s = dot4h(wrow[i], hh[i], s);
        s += __shfl_xor(s, 1);
        s += __shfl_xor(s, 2);
        if (q == 0){ if (gr < 24) giA_l[gr] = s; else ghB_l[gr-24] = s; }
      }
      __syncthreads();                                   // bar4
    }

  } else if (role == 1){
    // ================================================== featgx role
    const int t = idx;
    { int j = tid >> 1, s = tid & 1;
      const float4* a4 = reinterpret_cast<const float4*>(v0 + (size_t)t*VIN) + s*96;
      const float4* w4 = reinterpret_cast<const float4*>(W1v + (size_t)j*VIN) + s*96;
      float p = 0.f;
      #pragma unroll 4
      for (int c = 0; c < 96; ++c){
        float4 a = a4[c], w = w4[c];
        p += a.x*w.x + a.y*w.y + a.z*w.z + a.w*w.w;
      }
      p += __shfl_xor(p, 1);
      if (s == 0) xbuf[j] = eluf(p + b1v[j]);
    }
    if (tid < VF){
      float am = b1m[tid] + W1m[tid*2]*m0[t*2] + W1m[tid*2+1]*m0[t*2+1];
      xbuf[VF + tid] = eluf(am);
    }
    __syncthreads();
    #pragma unroll
    for (int k = 0; k < 3; ++k){
      int r = k*256 + tid;
      const float4* w4 = reinterpret_cast<const float4*>(Wih_low + (size_t)r*(2*H));
      const float4* x4 = reinterpret_cast<const float4*>(xbuf);
      float acc = bih_low[r];
      #pragma unroll 8
      for (int c = 0; c < 64; ++c){
        float4 w = w4[c], x = x4[c];
        acc += w.x*x.x + w.y*x.y + w.z*x.z + w.w*x.w;
      }
      ast(gxt + (size_t)t*G3 + r, packtv(1u, acc));
    }

  } else {
    // ================================================== post role
    const int t = idx;
    for (int i = 0; i < t; ++i) __builtin_amdgcn_s_sleep(32);   // staggered start
    if (wv == 0){
      const u64* p = h1ot + (size_t)t*H + lane;
      int guard = 0;
      while (true){
        u64 x0 = ald(p), x1 = ald(p+64), x2 = ald(p+128), x3 = ald(p+192);
        bool ok = (((unsigned)(x0>>32))==1u) & (((unsigned)(x1>>32))==1u)
                & (((unsigned)(x2>>32))==1u) & (((unsigned)(x3>>32))==1u);
        if (ok | (++guard > BAIL)){
          xbuf[      lane] = eluf(unpackv(x0));
          xbuf[ 64 + lane] = eluf(unpackv(x1));
          xbuf[128 + lane] = eluf(unpackv(x2));
          xbuf[192 + lane] = eluf(unpackv(x3));
          break;
        }
        __builtin_amdgcn_s_sleep(8);
      }
    }
    __syncthreads();
    #pragma unroll
    for (int k = 0; k < 3; ++k){
      int r = k*256 + tid;
      const float4* w4 = reinterpret_cast<const float4*>(W2v + (size_t)r*VF);
      const float4* f4 = reinterpret_cast<const float4*>(xbuf);
      float acc = b2v[r];
      #pragma unroll 8
      for (int c = 0; c < 32; ++c){
        float4 w = w4[c], x = f4[c];
        acc += w.x*x.x + w.y*x.y + w.z*x.z + w.w*x.w;
      }
      out[(size_t)t*VIN + r] = sigm(acc);
    }
    if (tid < MIN_){
      const float* wm = W2m + tid*VF;
      float am = b2m[tid];
      #pragma unroll 8
      for (int c = 0; c < VF; ++c) am += wm[c] * xbuf[VF + c];
      out[(size_t)T_STEPS*VIN + t*MIN_ + tid] = tanhf(am);
    }
  }
}

extern "C" void kernel_launch(void* const* d_in, const int* in_sizes, int n_in,
                              void* d_out, int out_size, void* d_ws, size_t ws_size,
                              hipStream_t stream)
{
  const float* v0       = (const float*)d_in[0];
  const float* m0       = (const float*)d_in[1];
  const float* W1v      = (const float*)d_in[2];
  const float* b1v      = (const float*)d_in[3];
  const float* W1m      = (const float*)d_in[4];
  const float* b1m      = (const float*)d_in[5];
  const float* Wih_low  = (const float*)d_in[6];
  const float* Whh_low  = (const float*)d_in[7];
  const float* bih_low  = (const float*)d_in[8];
  const float* bhh_low  = (const float*)d_in[9];
  const float* Wih_high = (const float*)d_in[10];
  const float* Whh_high = (const float*)d_in[11];
  const float* bih_high = (const float*)d_in[12];
  const float* bhh_high = (const float*)d_in[13];
  const float* W2v      = (const float*)d_in[14];
  const float* b2v      = (const float*)d_in[15];
  const float* W2m      = (const float*)d_in[16];
  const float* b2m      = (const float*)d_in[17];
  float* out = (float*)d_out;

  // ws layout (8B-aligned). Poison 0xAA..AA != any tag used (1..50).
  // h1s/h2s: [par][128] u64 f16-packed tagged data, single copy (2 KB each).
  char* ws = (char*)d_ws;
  u64* h1s      = (u64*)(ws + 0);               // 2 KB
  u64* h2s      = (u64*)(ws + 2048);            // 2 KB
  u64* gxt      = (u64*)(ws + 4096);            // 300 KB
  u64* h1ot     = (u64*)(ws + 311296);          // 100 KB
  unsigned* ectl= (unsigned*)(ws + 413696);     // election state

  hipMemsetAsync(ws + 413696, 0, 256, stream);  // zero election state only

  fused_kernel<<<NBLOCKS, BT, 0, stream>>>(
      v0, m0, W1v, b1v, W1m, b1m,
      Wih_low, Whh_low, bih_low, bhh_low,
      Wih_high, Whh_high, bih_high, bhh_high,
      W2v, b2v, W2m, b2m, out,
      h1s, h2s, gxt, h1ot, ectl);
}